// Round 8
// baseline (597.720 us; speedup 1.0000x reference)
//
#include <hip/hip_runtime.h>
#include <hip/hip_bf16.h>

// Net_79018808312147 — R8: split-K column-slice streaming.
// R7 (row-per-wave, 8-deep prefetch) = ~163 us kernel time (~3.7 TB/s).
// Depth scaling has flattened (R3 2.2 -> R7 3.7 TB/s for 8x depth), so the
// residual is access pattern / per-iter overhead. R8 makes each block walk
// its 256 KB W panel (and O panel) LINEARLY like the 6.6 TB/s fill kernel:
// wave w owns columns [w*256, w*256+256) of all 16 block rows; iteration r
// reads one contiguous 16 KB row block-wide. Input slice lives in 4 regs
// (zero LDS traffic in the stream loop); inner iter = 2 float4 loads +
// 4 mul + 4 fma. Reduction is a one-time tail (butterfly + LDS transpose).

#define DD 4096
#define BLOCK 1024   // 16 waves
#define GRID  256    // 16 rows per block
#define RPB   16     // rows per block

template<bool MASKED>
__global__ __launch_bounds__(BLOCK, 4)   // VGPR cap 128, 1 block/CU
void gemv_kernel(const float* __restrict__ W,
                 const float* __restrict__ O,
                 const float* __restrict__ bias,
                 const float* __restrict__ src,   // prev buffer (or x)
                 const int*   __restrict__ g,     // gather idx (null layer 0)
                 const int*   __restrict__ s,     // scatter idx (null final)
                 float*       __restrict__ dst)
{
    __shared__ float sh[DD];
    __shared__ float partial[RPB][RPB + 1];   // [row][wave], padded
    const int tid  = threadIdx.x;
    const int lane = tid & 63;
    const int wv   = tid >> 6;                // 0..15
    const int row0 = blockIdx.x * RPB;

    // Stage (gathered) input vector into LDS once: 16 KiB.
    #pragma unroll
    for (int j = tid; j < DD; j += BLOCK)
        sh[j] = MASKED ? src[g[j]] : src[j];
    __syncthreads();

    // This lane's column slice, held in registers for the whole kernel.
    const int col = wv * 256 + lane * 4;
    const float4 v = *reinterpret_cast<const float4*>(sh + col);

    const float* __restrict__ Wp = W + (size_t)row0 * DD + col;
    const float* __restrict__ Op = MASKED ? (O + (size_t)row0 * DD + col)
                                          : nullptr;

    // Stream 16 rows; per r the whole block reads one contiguous 16 KB row.
    float acc[RPB];
    #pragma unroll
    for (int r = 0; r < RPB; ++r) {
        float4 w = *reinterpret_cast<const float4*>(Wp + (size_t)r * DD);
        if (MASKED) {
            float4 o = *reinterpret_cast<const float4*>(Op + (size_t)r * DD);
            w.x *= o.x; w.y *= o.y; w.z *= o.z; w.w *= o.w;
        }
        acc[r] = fmaf(w.x, v.x, fmaf(w.y, v.y, fmaf(w.z, v.z, w.w * v.w)));
    }

    // Tail: butterfly-reduce each row partial across the 64 lanes.
    #pragma unroll
    for (int r = 0; r < RPB; ++r) {
        float a = acc[r];
        #pragma unroll
        for (int off = 32; off; off >>= 1)
            a += __shfl_xor(a, off, 64);
        if (lane == 0) partial[r][wv] = a;
    }
    __syncthreads();

    // Combine the 16 wave-slices per row, bias + relu, scatter/store.
    if (tid < RPB) {
        const int r = row0 + tid;
        float t = 0.f;
        #pragma unroll
        for (int w2 = 0; w2 < RPB; ++w2) t += partial[tid][w2];
        t = fmaxf(t + bias[r], 0.f);
        if (s) dst[s[r]] = t;     // scatter (permutation) into next buffer
        else   dst[r]    = t;     // final layer: pre-scatter output
    }
}

extern "C" void kernel_launch(void* const* d_in, const int* in_sizes, int n_in,
                              void* d_out, int out_size, void* d_ws, size_t ws_size,
                              hipStream_t stream) {
    const float* x       = (const float*)d_in[0];
    const float* W_in    = (const float*)d_in[1];
    const float* b_in    = (const float*)d_in[2];
    const float* weights = (const float*)d_in[3];
    const float* orders  = (const float*)d_in[4];
    const float* biases  = (const float*)d_in[5];
    const int*   gidx    = (const int*)d_in[6];
    const int*   sidx    = (const int*)d_in[7];
    float*       out     = (float*)d_out;

    float* buf0 = (float*)d_ws;
    float* buf1 = buf0 + DD;

    // Input layer: relu(W_in @ x + b_in), scattered by scatter_idx[0].
    gemv_kernel<false><<<GRID, BLOCK, 0, stream>>>(
        W_in, nullptr, b_in, x, nullptr, sidx, buf0);

    float* cur = buf0;
    float* nxt = buf1;
    for (int l = 0; l < 4; ++l) {
        const int* s  = (l == 3) ? nullptr : (sidx + (size_t)(l + 1) * DD);
        float*     d  = (l == 3) ? out     : nxt;
        gemv_kernel<true><<<GRID, BLOCK, 0, stream>>>(
            weights + (size_t)l * DD * DD,
            orders  + (size_t)l * DD * DD,
            biases  + (size_t)l * DD,
            cur, gidx + (size_t)l * DD, s, d);
        float* t = cur; cur = nxt; nxt = t;
    }
}

// Round 9
// 553.534 us; speedup vs baseline: 1.0798x; 1.0798x over previous
//
#include <hip/hip_runtime.h>
#include <hip/hip_bf16.h>

// Net_79018808312147 — R9: device-linear row sweep.
// Evidence: R7 (per-wave-contiguous, scattered device order) = 163 us kernel;
// R8 (per-block contiguous, per-wave strided) = 214 us -> wave contiguity is
// mandatory. In-flight depth is NOT the limiter (128 KB/CU >> 25 KB needed).
// Remaining lever: device-level ordering. R9: at iter t, block b does row
// t*256+b; waves cover the row's 16 contiguous 1KB chunks. Device-wide each
// iteration reads one contiguous 4 MB slab of W (and O) front-to-back, like
// the 6.6 TB/s fill kernel. Wave w always owns column chunk w -> input slice
// in 4 regs, zero LDS in stream loop; one __syncthreads per kernel for the
// cross-wave combine.

#define DD 4096
#define BLOCK 1024   // 16 waves = 16 x 1KB chunks = one full row per iter
#define GRID  256    // block b + iter t -> row t*256+b; 16 iters
#define ITERS 16

template<bool MASKED>
__global__ __launch_bounds__(BLOCK, 4)   // VGPR cap 128, 1 block/CU
void gemv_kernel(const float* __restrict__ W,
                 const float* __restrict__ O,
                 const float* __restrict__ bias,
                 const float* __restrict__ src,   // prev buffer (or x)
                 const int*   __restrict__ g,     // gather idx (null layer 0)
                 const int*   __restrict__ s,     // scatter idx (null final)
                 float*       __restrict__ dst)
{
    __shared__ float sh[DD];
    __shared__ float partial[ITERS][17];      // [iter][wave], padded
    const int tid  = threadIdx.x;
    const int lane = tid & 63;
    const int wv   = tid >> 6;                // 0..15 = column chunk
    const int bid  = blockIdx.x;

    // Stage (gathered) input vector into LDS once.
    #pragma unroll
    for (int j = tid; j < DD; j += BLOCK)
        sh[j] = MASKED ? src[g[j]] : src[j];
    __syncthreads();

    // Wave w's column slice is fixed for all rows -> keep in registers.
    const int col = wv * 256 + lane * 4;
    const float4 v = *reinterpret_cast<const float4*>(sh + col);

    const float* __restrict__ Wc = W + col;
    const float* __restrict__ Oc = MASKED ? (O + col) : nullptr;

    // Stream 16 rows, stride 256 rows (1 MB): device-wide, iteration t reads
    // the contiguous slab rows [t*256, t*256+256) in block order.
    #pragma unroll
    for (int t = 0; t < ITERS; ++t) {
        const size_t roff = ((size_t)t * GRID + bid) * DD;
        float4 w = *reinterpret_cast<const float4*>(Wc + roff);
        if (MASKED) {
            float4 o = *reinterpret_cast<const float4*>(Oc + roff);
            w.x *= o.x; w.y *= o.y; w.z *= o.z; w.w *= o.w;
        }
        float p = fmaf(w.x, v.x, fmaf(w.y, v.y, fmaf(w.z, v.z, w.w * v.w)));
        #pragma unroll
        for (int off = 32; off; off >>= 1)
            p += __shfl_xor(p, off, 64);
        if (lane == 0) partial[t][wv] = p;    // no sync needed until the end
    }
    __syncthreads();

    // Thread t finalizes row t*256+bid: sum 16 wave partials, bias+relu, store.
    if (tid < ITERS) {
        const int r = tid * GRID + bid;
        float acc = 0.f;
        #pragma unroll
        for (int w2 = 0; w2 < ITERS; ++w2) acc += partial[tid][w2];
        acc = fmaxf(acc + bias[r], 0.f);
        if (s) dst[s[r]] = acc;   // scatter (permutation) into next buffer
        else   dst[r]    = acc;   // final layer: pre-scatter output
    }
}

extern "C" void kernel_launch(void* const* d_in, const int* in_sizes, int n_in,
                              void* d_out, int out_size, void* d_ws, size_t ws_size,
                              hipStream_t stream) {
    const float* x       = (const float*)d_in[0];
    const float* W_in    = (const float*)d_in[1];
    const float* b_in    = (const float*)d_in[2];
    const float* weights = (const float*)d_in[3];
    const float* orders  = (const float*)d_in[4];
    const float* biases  = (const float*)d_in[5];
    const int*   gidx    = (const int*)d_in[6];
    const int*   sidx    = (const int*)d_in[7];
    float*       out     = (float*)d_out;

    float* buf0 = (float*)d_ws;
    float* buf1 = buf0 + DD;

    // Input layer: relu(W_in @ x + b_in), scattered by scatter_idx[0].
    gemv_kernel<false><<<GRID, BLOCK, 0, stream>>>(
        W_in, nullptr, b_in, x, nullptr, sidx, buf0);

    float* cur = buf0;
    float* nxt = buf1;
    for (int l = 0; l < 4; ++l) {
        const int* s  = (l == 3) ? nullptr : (sidx + (size_t)(l + 1) * DD);
        float*     d  = (l == 3) ? out     : nxt;
        gemv_kernel<true><<<GRID, BLOCK, 0, stream>>>(
            weights + (size_t)l * DD * DD,
            orders  + (size_t)l * DD * DD,
            biases  + (size_t)l * DD,
            cur, gidx + (size_t)l * DD, s, d);
        float* t = cur; cur = nxt; nxt = t;
    }
}